// Round 2
// baseline (225.596 us; speedup 1.0000x reference)
//
#include <hip/hip_runtime.h>

// IPC point-edge barrier energy, MI355X.
// Inputs (setup_inputs order):
//   d_in[0] Uu              float32 [N_VERTS*2]
//   d_in[1] rest_positions  float32 [N_VERTS*2]
//   d_in[2] pair_v          int32   [N_PAIRS]
//   d_in[3] pair_e0         int32   [N_PAIRS]
//   d_in[4] pair_e1         int32   [N_PAIRS]
// Output: scalar float32 barrier energy.
//
// R1 analysis: pairs_k was latency-bound (HBM 6%, VALU 10%) — the 100 MB
// index stream thrashes the per-XCD 4 MiB L2, evicting the 2 MB coords
// table, so the 25.2M random float2 gathers pay L3/HBM latency.
// R2: (a) non-temporal index loads (keep coords L2-resident),
//     (b) 2x unroll -> 24 gathers in flight per thread (MLP),
//     (c) fold out-zeroing into coords_k (one fewer dispatch).

constexpr int N_VERTS = 262144;
constexpr int N_PAIRS = 8388608;
constexpr float DHAT2 = 0.05f * 0.05f;       // 0.0025
constexpr float INV_DHAT2 = 1.0f / DHAT2;    // 400
constexpr float EPSF = 1e-12f;

typedef int v4i __attribute__((ext_vector_type(4)));

// ---------------------------------------------------------------------------
// Kernel A: coords = rest + Uu  (524288 floats = 131072 float4); also zero out.
// ---------------------------------------------------------------------------
__global__ __launch_bounds__(256) void coords_k(const float4* __restrict__ Uu,
                                                const float4* __restrict__ rest,
                                                float4* __restrict__ coords,
                                                float* __restrict__ out,
                                                int out_n) {
    int i = blockIdx.x * blockDim.x + threadIdx.x;
    float4 u = Uu[i];
    float4 r = rest[i];
    coords[i] = make_float4(u.x + r.x, u.y + r.y, u.z + r.z, u.w + r.w);
    if (blockIdx.x == 0 && threadIdx.x < (unsigned)out_n) out[threadIdx.x] = 0.0f;
}

// ---------------------------------------------------------------------------
// Kernel B: per-pair barrier + reduction. 8 pairs/thread/iter.
// ---------------------------------------------------------------------------
__global__ __launch_bounds__(256) void pairs_k(const float2* __restrict__ coords,
                                               const v4i* __restrict__ pv,
                                               const v4i* __restrict__ pe0,
                                               const v4i* __restrict__ pe1,
                                               float* __restrict__ out) {
    float acc = 0.0f;
    const int nquads = N_PAIRS / 4;                    // 2097152
    const int stride = gridDim.x * blockDim.x;         // 524288 at 2048x256
    const int tid = blockIdx.x * blockDim.x + threadIdx.x;

    // nquads == 4*stride at the chosen grid: each thread runs this loop twice,
    // handling quads {q0, q0+stride}. Guards kept for generality (wave-uniform
    // in practice).
    for (int q0 = tid; q0 < nquads; q0 += 2 * stride) {
        const int q1 = q0 + stride;
        const bool two = (q1 < nquads);

        // --- streaming index loads (non-temporal: don't evict coords in L2)
        v4i v0 = __builtin_nontemporal_load(pv + q0);
        v4i a0 = __builtin_nontemporal_load(pe0 + q0);
        v4i b0 = __builtin_nontemporal_load(pe1 + q0);
        v4i v1 = {}, a1 = {}, b1 = {};
        if (two) {
            v1 = __builtin_nontemporal_load(pv + q1);
            a1 = __builtin_nontemporal_load(pe0 + q1);
            b1 = __builtin_nontemporal_load(pe1 + q1);
        }

        int vi[8] = {v0.x, v0.y, v0.z, v0.w, v1.x, v1.y, v1.z, v1.w};
        int ai[8] = {a0.x, a0.y, a0.z, a0.w, a1.x, a1.y, a1.z, a1.w};
        int bi[8] = {b0.x, b0.y, b0.z, b0.w, b1.x, b1.y, b1.z, b1.w};

        const int np = two ? 8 : 4;

        // --- issue all gathers first (24 loads in flight -> MLP)
        float2 P[8], A[8], B[8];
#pragma unroll
        for (int k = 0; k < 8; ++k) {
            if (k < np) {
                P[k] = coords[vi[k]];
                A[k] = coords[ai[k]];
                B[k] = coords[bi[k]];
            }
        }

        // --- compute
#pragma unroll
        for (int k = 0; k < 8; ++k) {
            if (k < np) {
                float abx = B[k].x - A[k].x, aby = B[k].y - A[k].y;
                float apx = P[k].x - A[k].x, apy = P[k].y - A[k].y;

                float denom = fmaxf(abx * abx + aby * aby, EPSF);
                float t = (apx * abx + apy * aby) / denom;
                t = fminf(fmaxf(t, 0.0f), 1.0f);

                float dx = apx - t * abx;
                float dy = apy - t * aby;
                float d2 = dx * dx + dy * dy;

                float d2s = fmaxf(d2, EPSF);
                float dm = d2s - DHAT2;
                float term = -(dm * dm) * __logf(d2s * INV_DHAT2);
                acc += (d2 < DHAT2) ? term : 0.0f;
            }
        }
    }

    // wave (64-lane) shuffle reduction
#pragma unroll
    for (int off = 32; off > 0; off >>= 1)
        acc += __shfl_down(acc, off, 64);

    __shared__ float wsum[4];  // 256 threads = 4 waves
    int lane = threadIdx.x & 63;
    int wave = threadIdx.x >> 6;
    if (lane == 0) wsum[wave] = acc;
    __syncthreads();

    if (threadIdx.x == 0) {
        float s = wsum[0] + wsum[1] + wsum[2] + wsum[3];
        atomicAdd(out, s);
    }
}

// ---------------------------------------------------------------------------
extern "C" void kernel_launch(void* const* d_in, const int* in_sizes, int n_in,
                              void* d_out, int out_size, void* d_ws, size_t ws_size,
                              hipStream_t stream) {
    const float* Uu   = (const float*)d_in[0];
    const float* rest = (const float*)d_in[1];
    const int*   pv   = (const int*)d_in[2];
    const int*   pe0  = (const int*)d_in[3];
    const int*   pe1  = (const int*)d_in[4];
    float* out = (float*)d_out;

    float* coords = (float*)d_ws;  // 2 MB: N_VERTS * 2 floats

    // coords = rest + Uu; also zeroes out[] (d_out is poisoned before replay)
    {
        int nvec = (N_VERTS * 2) / 4;  // 131072
        coords_k<<<nvec / 256, 256, 0, stream>>>(
            (const float4*)Uu, (const float4*)rest, (float4*)coords, out, out_size);
    }

    // barrier energy
    {
        int blocks = 2048;  // 8 blocks/CU (32 waves/CU cap); one atomic per block
        pairs_k<<<blocks, 256, 0, stream>>>(
            (const float2*)coords, (const v4i*)pv, (const v4i*)pe0,
            (const v4i*)pe1, out);
    }
}